// Round 3
// baseline (358.210 us; speedup 1.0000x reference)
//
#include <hip/hip_runtime.h>
#include <stdint.h>

// Problem constants
#define B_ 64
#define T_ 512
#define D_ 1024
#define S_ 1024
#define U_ 10

typedef float f32x2 __attribute__((ext_vector_type(2)));
typedef float f32x4 __attribute__((ext_vector_type(4)));

// workspace layout (in floats)
static constexpr int WS_PMZ = 0;                      // [512][2]  per-block (m, Z)
static constexpr int WS_E   = 1024;                   // [64][512] raw e values
static constexpr int WS_PV  = 33792;                  // [512][1024] partial weighted sums
static constexpr int WS_C   = 33792 + 512 * 1024;     // [64][10]  c[u] per batch

// ---------------------------------------------------------------------------
// DPP wave64 reductions
// ---------------------------------------------------------------------------
template <int CTRL>
__device__ __forceinline__ float dpp_add(float x) {
    int yi = __builtin_amdgcn_update_dpp(0, __float_as_int(x), CTRL, 0xf, 0xf, true);
    return x + __int_as_float(yi);
}
template <int CTRL>
__device__ __forceinline__ float dpp_max(float x) {
    int yi = __builtin_amdgcn_update_dpp(__float_as_int(-1e30f), __float_as_int(x),
                                         CTRL, 0xf, 0xf, true);
    return fmaxf(x, __int_as_float(yi));
}

__device__ __forceinline__ float wave_sum63(float x) {
    x = dpp_add<0x111>(x);
    x = dpp_add<0x112>(x);
    x = dpp_add<0x114>(x);
    x = dpp_add<0x118>(x);
    x = dpp_add<0x142>(x);
    x = dpp_add<0x143>(x);
    return x;   // lane 63 = total
}
__device__ __forceinline__ float wave_sum_uniform(float x) {
    return __int_as_float(__builtin_amdgcn_readlane(__float_as_int(wave_sum63(x)), 63));
}
__device__ __forceinline__ float wave_max_uniform(float x) {
    x = dpp_max<0x111>(x);
    x = dpp_max<0x112>(x);
    x = dpp_max<0x114>(x);
    x = dpp_max<0x118>(x);
    x = dpp_max<0x142>(x);
    x = dpp_max<0x143>(x);
    return __int_as_float(__builtin_amdgcn_readlane(__float_as_int(x), 63));
}

__device__ __forceinline__ f32x2 pk_fma(f32x2 a, f32x2 b, f32x2 c) {
#if __has_builtin(__builtin_elementwise_fma)
    return __builtin_elementwise_fma(a, b, c);
#else
    return a * b + c;
#endif
}

// ---------------------------------------------------------------------------
// K0: c[b][u] = s_prev[b]·W1[D:,u] + b1[u]   (64 blocks x 256 threads)
// ---------------------------------------------------------------------------
__global__ __launch_bounds__(256) void k0_prep(const float* __restrict__ s_prev,
                                               const float* __restrict__ W1,
                                               const float* __restrict__ b1,
                                               float* __restrict__ ws) {
    const int b    = blockIdx.x;
    const int tid  = threadIdx.x;
    const int wave = tid >> 6;
    const int lane = tid & 63;

    f32x2 acc2[5];
#pragma unroll
    for (int h = 0; h < 5; h++) acc2[h] = f32x2{0.f, 0.f};

    const f32x4 s4 = *(const f32x4*)(s_prev + b * S_ + tid * 4);
    const float sv[4] = {s4.x, s4.y, s4.z, s4.w};
#pragma unroll
    for (int i = 0; i < 4; i++) {
        const float* wp = W1 + (size_t)(D_ + tid * 4 + i) * U_;
        const f32x2 svv = f32x2{sv[i], sv[i]};
#pragma unroll
        for (int h = 0; h < 5; h++)
            acc2[h] = pk_fma(svv, *(const f32x2*)(wp + 2 * h), acc2[h]);
    }

    __shared__ float red[4][U_];
    const float vals[U_] = {acc2[0].x, acc2[0].y, acc2[1].x, acc2[1].y, acc2[2].x,
                            acc2[2].y, acc2[3].x, acc2[3].y, acc2[4].x, acc2[4].y};
#pragma unroll
    for (int u = 0; u < U_; u++) {
        float s = wave_sum63(vals[u]);
        if (lane == 63) red[wave][u] = s;
    }
    __syncthreads();
    if (tid < U_)
        ws[WS_C + b * U_ + tid] =
            red[0][tid] + red[1][tid] + red[2][tid] + red[3][tid] + b1[tid];
}

// ---------------------------------------------------------------------------
// K1: 512 blocks = 64 b x 8 chunks of 64 t. ONE wave per block; lane owns one t.
//  - a staged via global_load_lds (linear dest, XOR-swizzled source), dbuf,
//    counted vmcnt(16) so 16 loads always stay in flight (T4).
//  - dot accumulated IN-LANE (no cross-lane reduce); W1 via uniform s_loads.
//  - exact softmax over the 64 lane-t's: one DPP max + one DPP sum per block.
//  - weighted sum re-reads the block's 256 KB from L3 (no HBM re-fetch).
// ---------------------------------------------------------------------------
__global__ __launch_bounds__(64) void k1_main(const float* __restrict__ a,
                                              const float* __restrict__ W1,
                                              const float* __restrict__ W2,
                                              const float* __restrict__ b2,
                                              float* __restrict__ ws) {
    const int blk  = blockIdx.x;
    const int b    = blk >> 3;
    const int p    = blk & 7;
    const int lane = threadIdx.x;   // 0..63, owns t = t0 + lane

    __shared__ __align__(16) float tile[2][4096];   // [buf][64 t-rows x 64 floats]
    __shared__ float wbuf[64];

    const int t0 = p * 64;
    const size_t arow0 = (size_t)(b * T_ + t0) * D_;   // floats

    // stage addressing: dest chunk k (1 KB) covers rows r=4k..4k+3; lane's 16B
    // lands at (r = 4k + (lane>>4), physslot = lane&15). Source col-slot =
    // physslot ^ (r&15)  (involution; read side applies the same XOR).
    const int rs  = lane >> 4;
    const int s15 = lane & 15;
    int col_m[4];
#pragma unroll
    for (int m2 = 0; m2 < 4; m2++) col_m[m2] = s15 ^ ((4 * m2 + rs) & 15);

    auto stage = [&](int buf, int sc) {
#pragma unroll
        for (int k = 0; k < 16; k++) {
            const float* src =
                a + arow0 + (size_t)(4 * k + rs) * D_ + sc * 64 + col_m[k & 3] * 4;
            __builtin_amdgcn_global_load_lds(
                (const __attribute__((address_space(1))) uint32_t*)src,
                (__attribute__((address_space(3))) uint32_t*)&tile[buf][k * 256],
                16, 0, 0);
        }
    };

    f32x2 acc2[5];   // dot partial, u-pairs
#pragma unroll
    for (int h = 0; h < 5; h++) acc2[h] = f32x2{0.f, 0.f};

    stage(0, 0);

#pragma unroll
    for (int sc = 0; sc < 16; sc++) {
        if (sc < 15) {
            stage((sc + 1) & 1, sc + 1);
            asm volatile("s_waitcnt vmcnt(16)" ::: "memory");   // cur's 16 done
        } else {
            asm volatile("s_waitcnt vmcnt(0)" ::: "memory");
        }
        __builtin_amdgcn_sched_barrier(0);

        const float* tb   = &tile[sc & 1][0];
        const float* wrow = W1 + (size_t)sc * 64 * U_;
#pragma unroll
        for (int j = 0; j < 16; j++) {
            const f32x4 av = *(const f32x4*)(tb + lane * 64 + ((j ^ s15) << 2));
            const float* wd = wrow + j * 4 * U_;   // uniform -> s_load
            const float avv[4] = {av.x, av.y, av.z, av.w};
#pragma unroll
            for (int i = 0; i < 4; i++) {
                const f32x2 axx = f32x2{avv[i], avv[i]};
#pragma unroll
                for (int h = 0; h < 5; h++)
                    acc2[h] = pk_fma(axx, *(const f32x2*)(wd + i * U_ + 2 * h), acc2[h]);
            }
        }
    }

    // ---- e for this lane's t ----
    const float* cb = ws + WS_C + b * U_;   // uniform
    const float xs[U_] = {acc2[0].x, acc2[0].y, acc2[1].x, acc2[1].y, acc2[2].x,
                          acc2[2].y, acc2[3].x, acc2[3].y, acc2[4].x, acc2[4].y};
    float e = b2[0];
#pragma unroll
    for (int u = 0; u < U_; u++) {
        float x = xs[u] + cb[u];
        // tanh(x) = 1 - 2/(e^{2x}+1); exp2 saturates -> exact +-1 tails
        float ex = exp2f(x * 2.8853900817779268f);
        float th = 1.f - 2.f * __builtin_amdgcn_rcpf(ex + 1.f);
        e += th * W2[u];
    }
    e = fmaxf(e, 0.f);
    ws[WS_E + b * T_ + t0 + lane] = e;

    // ---- exact softmax across the block's 64 t (once, not per-t) ----
    const float mb = wave_max_uniform(e);
    const float w  = exp2f((e - mb) * 1.4426950408889634f);
    const float Zb = wave_sum_uniform(w);
    wbuf[lane] = w;
    asm volatile("s_waitcnt lgkmcnt(0)" ::: "memory");   // single wave: no barrier

    // ---- weighted sum: lane owns d = {q*256 + lane*4}, a re-read from L3 ----
    f32x4 v[4];
#pragma unroll
    for (int q = 0; q < 4; q++) v[q] = f32x4{0.f, 0.f, 0.f, 0.f};

    const float* ab = a + arow0 + lane * 4;
#pragma unroll 8
    for (int t = 0; t < 64; t++) {
        const float wt = wbuf[t];   // uniform-address broadcast
        const float* ar = ab + (size_t)t * D_;
#pragma unroll
        for (int q = 0; q < 4; q++) {
            const f32x4 av = *(const f32x4*)(ar + q * 256);
            v[q] += wt * av;
        }
    }

#pragma unroll
    for (int q = 0; q < 4; q++)
        ((f32x4*)(ws + WS_PV))[blk * 256 + q * 64 + lane] = v[q];
    if (lane == 0) { ws[WS_PMZ + blk * 2] = mb; ws[WS_PMZ + blk * 2 + 1] = Zb; }
}

// ---------------------------------------------------------------------------
// K2: final combine per batch (8 partials) -> context + scores
// ---------------------------------------------------------------------------
__global__ __launch_bounds__(256) void k2_final(const float* __restrict__ ws,
                                                float* __restrict__ out) {
    const int b = blockIdx.x;
    const int tid = threadIdx.x;

    float pm[8], pz[8];
    float mb = -1e30f;
#pragma unroll
    for (int p = 0; p < 8; p++) {
        pm[p] = ws[WS_PMZ + (b * 8 + p) * 2];
        pz[p] = ws[WS_PMZ + (b * 8 + p) * 2 + 1];
        mb = fmaxf(mb, pm[p]);
    }
    float f[8], Z = 0.f;
#pragma unroll
    for (int p = 0; p < 8; p++) { f[p] = __expf(pm[p] - mb); Z += f[p] * pz[p]; }
    const float rz = 1.f / Z;

    f32x4 o = f32x4{0.f, 0.f, 0.f, 0.f};
#pragma unroll
    for (int p = 0; p < 8; p++) {
        f32x4 t = ((const f32x4*)(ws + WS_PV))[(b * 8 + p) * 256 + tid];
        o += f[p] * t;
    }
    o *= rz;
    ((f32x4*)out)[b * 256 + tid] = o;

    for (int t = tid; t < T_; t += 256) {
        out[B_ * D_ + b * T_ + t] = __expf(ws[WS_E + b * T_ + t] - mb) * rz;
    }
}

// ---------------------------------------------------------------------------
extern "C" void kernel_launch(void* const* d_in, const int* in_sizes, int n_in,
                              void* d_out, int out_size, void* d_ws, size_t ws_size,
                              hipStream_t stream) {
    const float* a      = (const float*)d_in[0];
    const float* s_prev = (const float*)d_in[1];
    const float* W1     = (const float*)d_in[2];
    const float* b1     = (const float*)d_in[3];
    const float* W2     = (const float*)d_in[4];
    const float* b2     = (const float*)d_in[5];
    float* out = (float*)d_out;
    float* ws  = (float*)d_ws;

    k0_prep<<<dim3(B_), dim3(256), 0, stream>>>(s_prev, W1, b1, ws);
    k1_main<<<dim3(B_ * 8), dim3(64), 0, stream>>>(a, W1, W2, b2, ws);
    k2_final<<<dim3(B_), dim3(256), 0, stream>>>(ws, out);
}

// Round 4
// 245.574 us; speedup vs baseline: 1.4587x; 1.4587x over previous
//
#include <hip/hip_runtime.h>
#include <stdint.h>

// Problem constants
#define B_ 64
#define T_ 512
#define D_ 1024
#define S_ 1024
#define U_ 10

typedef float f32x2 __attribute__((ext_vector_type(2)));
typedef float f32x4 __attribute__((ext_vector_type(4)));

// workspace layout (in floats)
static constexpr int WS_PMZ = 0;                      // [512][2]  per-block (m, Z)
static constexpr int WS_E   = 1024;                   // [64][512] raw e values
static constexpr int WS_PV  = 33792;                  // [512][1024] partial weighted sums
static constexpr int WS_C   = 33792 + 512 * 1024;     // [64][10]  c[u] per batch

// ---------------------------------------------------------------------------
// DPP wave64 reductions
// ---------------------------------------------------------------------------
template <int CTRL>
__device__ __forceinline__ float dpp_add(float x) {
    int yi = __builtin_amdgcn_update_dpp(0, __float_as_int(x), CTRL, 0xf, 0xf, true);
    return x + __int_as_float(yi);
}
template <int CTRL>
__device__ __forceinline__ float dpp_max(float x) {
    int yi = __builtin_amdgcn_update_dpp(__float_as_int(-1e30f), __float_as_int(x),
                                         CTRL, 0xf, 0xf, true);
    return fmaxf(x, __int_as_float(yi));
}

__device__ __forceinline__ float wave_sum63(float x) {
    x = dpp_add<0x111>(x);
    x = dpp_add<0x112>(x);
    x = dpp_add<0x114>(x);
    x = dpp_add<0x118>(x);
    x = dpp_add<0x142>(x);
    x = dpp_add<0x143>(x);
    return x;   // lane 63 = total
}
__device__ __forceinline__ float wave_sum_uniform(float x) {
    return __int_as_float(__builtin_amdgcn_readlane(__float_as_int(wave_sum63(x)), 63));
}
__device__ __forceinline__ float wave_max_uniform(float x) {
    x = dpp_max<0x111>(x);
    x = dpp_max<0x112>(x);
    x = dpp_max<0x114>(x);
    x = dpp_max<0x118>(x);
    x = dpp_max<0x142>(x);
    x = dpp_max<0x143>(x);
    return __int_as_float(__builtin_amdgcn_readlane(__float_as_int(x), 63));
}

__device__ __forceinline__ f32x2 pk_fma(f32x2 a, f32x2 b, f32x2 c) {
#if __has_builtin(__builtin_elementwise_fma)
    return __builtin_elementwise_fma(a, b, c);
#else
    return a * b + c;
#endif
}

// ---------------------------------------------------------------------------
// K0: c[b][u] = s_prev[b]·W1[D:,u] + b1[u]   (64 blocks x 256 threads)
// ---------------------------------------------------------------------------
__global__ __launch_bounds__(256) void k0_prep(const float* __restrict__ s_prev,
                                               const float* __restrict__ W1,
                                               const float* __restrict__ b1,
                                               float* __restrict__ ws) {
    const int b    = blockIdx.x;
    const int tid  = threadIdx.x;
    const int wave = tid >> 6;
    const int lane = tid & 63;

    f32x2 acc2[5];
#pragma unroll
    for (int h = 0; h < 5; h++) acc2[h] = f32x2{0.f, 0.f};

    const f32x4 s4 = *(const f32x4*)(s_prev + b * S_ + tid * 4);
    const float sv[4] = {s4.x, s4.y, s4.z, s4.w};
#pragma unroll
    for (int i = 0; i < 4; i++) {
        const float* wp = W1 + (size_t)(D_ + tid * 4 + i) * U_;
        const f32x2 svv = f32x2{sv[i], sv[i]};
#pragma unroll
        for (int h = 0; h < 5; h++)
            acc2[h] = pk_fma(svv, *(const f32x2*)(wp + 2 * h), acc2[h]);
    }

    __shared__ float red[4][U_];
    const float vals[U_] = {acc2[0].x, acc2[0].y, acc2[1].x, acc2[1].y, acc2[2].x,
                            acc2[2].y, acc2[3].x, acc2[3].y, acc2[4].x, acc2[4].y};
#pragma unroll
    for (int u = 0; u < U_; u++) {
        float s = wave_sum63(vals[u]);
        if (lane == 63) red[wave][u] = s;
    }
    __syncthreads();
    if (tid < U_)
        ws[WS_C + b * U_ + tid] =
            red[0][tid] + red[1][tid] + red[2][tid] + red[3][tid] + b1[tid];
}

// ---------------------------------------------------------------------------
// K1: 512 blocks (64 b x 8 chunks of 64 t) x 4 waves. Wave w owns d-range
// [256w, 256w+256); lane owns t = t0 + lane (dot accumulated IN-LANE, no
// cross-lane reduce in the hot loop; W1 via wave-uniform s_loads).
//  - a staged per-wave in [64t][32d] = 8 KB chunks via global_load_lds
//    (linear LDS dest, XOR-pre-swizzled global source; read applies same XOR),
//    double-buffered, counted vmcnt(8). 8 waves/CU, 64 KB/CU loads in flight.
//  - partial dots combined via LDS pmat; wave 0 finishes e + exact softmax
//    (ONE DPP max+sum per block, not per t).
//  - weighted sum re-reads the block's 256 KB tile from L2/L3 (no HBM re-fetch).
// ---------------------------------------------------------------------------
__global__ __launch_bounds__(256, 2) void k1_main(const float* __restrict__ a,
                                                  const float* __restrict__ W1,
                                                  const float* __restrict__ W2,
                                                  const float* __restrict__ b2,
                                                  float* __restrict__ ws) {
    const int blk  = blockIdx.x;
    const int b    = blk >> 3;
    const int p    = blk & 7;
    const int tid  = threadIdx.x;
    const int wave = tid >> 6;
    const int lane = tid & 63;

    __shared__ __align__(16) float stg[4][2][2048];   // 64 KB staging
    __shared__ float pmat[4][64][U_];                 // 10 KB partial dots
    __shared__ float wbuf[64];

    const int t0 = p * 64;
    const size_t arow0 = (size_t)(b * T_ + t0) * D_;            // floats
    const int dof0 = __builtin_amdgcn_readfirstlane(wave * 256); // wave's d base (SGPR)

    // stage mapping: instruction k stages rows t_loc = 8k..8k+7 (128 B each).
    // lane l -> (row-in-group r = l>>3, phys 16B-slot s = l&7). LDS layout is
    // linear: byte(t_loc, s) = t_loc*128 + s*16. Phys slot s holds LOGICAL
    // d-slot s ^ (t_loc&7); since t_loc&7 == l>>3 for every k, the source
    // col-slot per lane is k-independent.
    const int rsub = lane >> 3;
    const int slog = (lane & 7) ^ rsub;   // logical 16B-slot this lane fetches

    auto stage = [&](int buf, int c) {
        const float* base = a + arow0 + (size_t)(dof0 + c * 32 + slog * 4);
        float* dst = &stg[wave][buf][0];
#pragma unroll
        for (int k = 0; k < 8; k++) {
            const float* src = base + (size_t)(8 * k + rsub) * D_;
            __builtin_amdgcn_global_load_lds(
                (const __attribute__((address_space(1))) uint32_t*)src,
                (__attribute__((address_space(3))) uint32_t*)(dst + k * 256),
                16, 0, 0);
        }
    };

    // ---- dot phase: in-lane over wave's 256 d, 8 chunks of 32 d ----
    f32x2 acc2[5];
#pragma unroll
    for (int h = 0; h < 5; h++) acc2[h] = f32x2{0.f, 0.f};

    stage(0, 0);

#pragma unroll 1
    for (int c = 0; c < 8; c++) {
        if (c < 7) {
            stage((c + 1) & 1, c + 1);
            asm volatile("s_waitcnt vmcnt(8)" ::: "memory");   // chunk c's 8 done
        } else {
            asm volatile("s_waitcnt vmcnt(0)" ::: "memory");
        }
        __builtin_amdgcn_sched_barrier(0);

        const float* tb    = &stg[wave][c & 1][lane * 32];       // my t-row
        const float* wbase = W1 + (size_t)(dof0 + c * 32) * U_;  // uniform
#pragma unroll
        for (int j = 0; j < 8; j++) {
            const f32x4 av = *(const f32x4*)(tb + ((j ^ (lane & 7)) << 2));
            const float* wd = wbase + j * 4 * U_;                // uniform -> s_load
            const float avv[4] = {av.x, av.y, av.z, av.w};
#pragma unroll
            for (int i = 0; i < 4; i++) {
                const f32x2 ax = f32x2{avv[i], avv[i]};
#pragma unroll
                for (int h = 0; h < 5; h++)
                    acc2[h] = pk_fma(ax, *(const f32x2*)(wd + i * U_ + 2 * h), acc2[h]);
            }
        }
    }

    // ---- write partial dots, combine across waves ----
#pragma unroll
    for (int h = 0; h < 5; h++)
        *(f32x2*)(&pmat[wave][lane][2 * h]) = acc2[h];
    __syncthreads();

    // ---- e + exact softmax (wave 0 only; one DPP max+sum per block) ----
    if (wave == 0) {
        const float* cb = ws + WS_C + b * U_;   // uniform
        float e = b2[0];
#pragma unroll
        for (int u = 0; u < U_; u++) {
            float x = pmat[0][lane][u] + pmat[1][lane][u] + pmat[2][lane][u] +
                      pmat[3][lane][u] + cb[u];
            // tanh(x) = 1 - 2/(e^{2x}+1); exp2 saturates -> exact +-1 tails
            float ex = exp2f(x * 2.8853900817779268f);
            float th = 1.f - 2.f * __builtin_amdgcn_rcpf(ex + 1.f);
            e += th * W2[u];
        }
        e = fmaxf(e, 0.f);
        ws[WS_E + b * T_ + t0 + lane] = e;

        const float mb = wave_max_uniform(e);
        const float w  = exp2f((e - mb) * 1.4426950408889634f);
        const float Zb = wave_sum_uniform(w);
        wbuf[lane] = w;
        if (lane == 0) { ws[WS_PMZ + blk * 2] = mb; ws[WS_PMZ + blk * 2 + 1] = Zb; }
    }
    __syncthreads();

    // ---- weighted sum: thread owns d = tid*4; tile re-read from L2/L3 ----
    f32x4 v0 = f32x4{0.f, 0.f, 0.f, 0.f};
    f32x4 v1 = f32x4{0.f, 0.f, 0.f, 0.f};
    const float* ap = a + arow0 + tid * 4;
#pragma unroll 8
    for (int t = 0; t < 64; t += 2) {
        v0 += wbuf[t]     * *(const f32x4*)(ap + (size_t)t * D_);
        v1 += wbuf[t + 1] * *(const f32x4*)(ap + (size_t)(t + 1) * D_);
    }
    ((f32x4*)(ws + WS_PV))[blk * 256 + tid] = v0 + v1;
}

// ---------------------------------------------------------------------------
// K2: final combine per batch (8 partials) -> context + scores
// ---------------------------------------------------------------------------
__global__ __launch_bounds__(256) void k2_final(const float* __restrict__ ws,
                                                float* __restrict__ out) {
    const int b = blockIdx.x;
    const int tid = threadIdx.x;

    float pm[8], pz[8];
    float mb = -1e30f;
#pragma unroll
    for (int p = 0; p < 8; p++) {
        pm[p] = ws[WS_PMZ + (b * 8 + p) * 2];
        pz[p] = ws[WS_PMZ + (b * 8 + p) * 2 + 1];
        mb = fmaxf(mb, pm[p]);
    }
    float f[8], Z = 0.f;
#pragma unroll
    for (int p = 0; p < 8; p++) { f[p] = __expf(pm[p] - mb); Z += f[p] * pz[p]; }
    const float rz = 1.f / Z;

    f32x4 o = f32x4{0.f, 0.f, 0.f, 0.f};
#pragma unroll
    for (int p = 0; p < 8; p++) {
        f32x4 t = ((const f32x4*)(ws + WS_PV))[(b * 8 + p) * 256 + tid];
        o += f[p] * t;
    }
    o *= rz;
    ((f32x4*)out)[b * 256 + tid] = o;

    for (int t = tid; t < T_; t += 256) {
        out[B_ * D_ + b * T_ + t] = __expf(ws[WS_E + b * T_ + t] - mb) * rz;
    }
}

// ---------------------------------------------------------------------------
extern "C" void kernel_launch(void* const* d_in, const int* in_sizes, int n_in,
                              void* d_out, int out_size, void* d_ws, size_t ws_size,
                              hipStream_t stream) {
    const float* a      = (const float*)d_in[0];
    const float* s_prev = (const float*)d_in[1];
    const float* W1     = (const float*)d_in[2];
    const float* b1     = (const float*)d_in[3];
    const float* W2     = (const float*)d_in[4];
    const float* b2     = (const float*)d_in[5];
    float* out = (float*)d_out;
    float* ws  = (float*)d_ws;

    k0_prep<<<dim3(B_), dim3(256), 0, stream>>>(s_prev, W1, b1, ws);
    k1_main<<<dim3(B_ * 8), dim3(256), 0, stream>>>(a, W1, W2, b2, ws);
    k2_final<<<dim3(B_), dim3(256), 0, stream>>>(ws, out);
}

// Round 5
// 221.072 us; speedup vs baseline: 1.6203x; 1.1108x over previous
//
#include <hip/hip_runtime.h>
#include <stdint.h>

// Problem constants
#define B_ 64
#define T_ 512
#define D_ 1024
#define S_ 1024
#define U_ 10

typedef float f32x2 __attribute__((ext_vector_type(2)));
typedef float f32x4 __attribute__((ext_vector_type(4)));

// workspace layout (in floats)
static constexpr int WS_PMZ = 0;                      // [512][2]  per-block (m, Z)
static constexpr int WS_E   = 1024;                   // [64][512] raw e values
static constexpr int WS_PV  = 33792;                  // [512][1024] partial weighted sums
static constexpr int WS_C   = 33792 + 512 * 1024;     // [64][10]  c[u] per batch

// ---------------------------------------------------------------------------
// DPP wave64 reductions
// ---------------------------------------------------------------------------
template <int CTRL>
__device__ __forceinline__ float dpp_add(float x) {
    int yi = __builtin_amdgcn_update_dpp(0, __float_as_int(x), CTRL, 0xf, 0xf, true);
    return x + __int_as_float(yi);
}
template <int CTRL>
__device__ __forceinline__ float dpp_max(float x) {
    int yi = __builtin_amdgcn_update_dpp(__float_as_int(-1e30f), __float_as_int(x),
                                         CTRL, 0xf, 0xf, true);
    return fmaxf(x, __int_as_float(yi));
}

__device__ __forceinline__ float wave_sum63(float x) {
    x = dpp_add<0x111>(x);
    x = dpp_add<0x112>(x);
    x = dpp_add<0x114>(x);
    x = dpp_add<0x118>(x);
    x = dpp_add<0x142>(x);
    x = dpp_add<0x143>(x);
    return x;   // lane 63 = total
}
__device__ __forceinline__ float wave_sum_uniform(float x) {
    return __int_as_float(__builtin_amdgcn_readlane(__float_as_int(wave_sum63(x)), 63));
}
__device__ __forceinline__ float wave_max_uniform(float x) {
    x = dpp_max<0x111>(x);
    x = dpp_max<0x112>(x);
    x = dpp_max<0x114>(x);
    x = dpp_max<0x118>(x);
    x = dpp_max<0x142>(x);
    x = dpp_max<0x143>(x);
    return __int_as_float(__builtin_amdgcn_readlane(__float_as_int(x), 63));
}

__device__ __forceinline__ f32x2 pk_fma(f32x2 a, f32x2 b, f32x2 c) {
#if __has_builtin(__builtin_elementwise_fma)
    return __builtin_elementwise_fma(a, b, c);
#else
    return a * b + c;
#endif
}

// ---------------------------------------------------------------------------
// K0: c[b][u] = s_prev[b]·W1[D:,u] + b1[u]   (64 blocks x 256 threads)
// ---------------------------------------------------------------------------
__global__ __launch_bounds__(256) void k0_prep(const float* __restrict__ s_prev,
                                               const float* __restrict__ W1,
                                               const float* __restrict__ b1,
                                               float* __restrict__ ws) {
    const int b    = blockIdx.x;
    const int tid  = threadIdx.x;
    const int wave = tid >> 6;
    const int lane = tid & 63;

    f32x2 acc2[5];
#pragma unroll
    for (int h = 0; h < 5; h++) acc2[h] = f32x2{0.f, 0.f};

    const f32x4 s4 = *(const f32x4*)(s_prev + b * S_ + tid * 4);
    const float sv[4] = {s4.x, s4.y, s4.z, s4.w};
#pragma unroll
    for (int i = 0; i < 4; i++) {
        const float* wp = W1 + (size_t)(D_ + tid * 4 + i) * U_;
        const f32x2 svv = f32x2{sv[i], sv[i]};
#pragma unroll
        for (int h = 0; h < 5; h++)
            acc2[h] = pk_fma(svv, *(const f32x2*)(wp + 2 * h), acc2[h]);
    }

    __shared__ float red[4][U_];
    const float vals[U_] = {acc2[0].x, acc2[0].y, acc2[1].x, acc2[1].y, acc2[2].x,
                            acc2[2].y, acc2[3].x, acc2[3].y, acc2[4].x, acc2[4].y};
#pragma unroll
    for (int u = 0; u < U_; u++) {
        float s = wave_sum63(vals[u]);
        if (lane == 63) red[wave][u] = s;
    }
    __syncthreads();
    if (tid < U_)
        ws[WS_C + b * U_ + tid] =
            red[0][tid] + red[1][tid] + red[2][tid] + red[3][tid] + b1[tid];
}

// ---------------------------------------------------------------------------
// K1: 512 blocks (64 b x 8 chunks of 64 t) x 2 waves. Wave w owns d-range
// [512w, 512w+512); lane owns t = t0 + lane (dot accumulated IN-LANE).
//  - W1[:D] preloaded to LDS once per block (40 KB); streamed per chunk via
//    wave-uniform ds_read (broadcast, conflict-free) -> kills the scalar-cache
//    s_load serialization that dominated round 3 (29k cyc/chunk).
//  - a staged per-wave in [64t][32d] = 8 KB chunks via global_load_lds
//    (linear dest, XOR-pre-swizzled source; read applies same XOR),
//    double-buffered, counted vmcnt(8).
//  - partial dots combined via pmat ALIASED onto the dead staging LDS.
//  - weighted sum re-reads the block's 256 KB tile from L2/L3.
// ---------------------------------------------------------------------------
__global__ __launch_bounds__(128) void k1_main(const float* __restrict__ a,
                                               const float* __restrict__ W1,
                                               const float* __restrict__ W2,
                                               const float* __restrict__ b2,
                                               float* __restrict__ ws) {
    const int blk  = blockIdx.x;
    const int b    = blk >> 3;
    const int p    = blk & 7;
    const int tid  = threadIdx.x;
    const int wave = tid >> 6;
    const int lane = tid & 63;

    __shared__ __align__(16) float w1s[D_ * U_];      // 40 KB W1[:D]
    __shared__ __align__(16) float stg[2][2][2048];   // 32 KB staging (2 waves x dbuf)
    __shared__ float wbuf[64];
    float* const pmat = &stg[0][0][0];                // aliased after dot phase: [2][64][10]

    const int t0 = p * 64;
    const size_t arow0 = (size_t)(b * T_ + t0) * D_;             // floats
    const int dof0 = __builtin_amdgcn_readfirstlane(wave * 512); // wave's d base

    // stage mapping (verified round 3): instr k stages rows 8k..8k+7 (128 B each).
    // lane l -> (row-in-group r = l>>3, phys 16B-slot s = l&7). Phys slot s of
    // row t holds LOGICAL d-slot s ^ (t&7); t&7 == l>>3 for every k.
    const int rsub = lane >> 3;
    const int slog = (lane & 7) ^ rsub;   // logical 16B-slot this lane fetches

    auto stage = [&](int buf, int c) {
        const float* base = a + arow0 + (size_t)(dof0 + c * 32 + slog * 4);
        float* dst = &stg[wave][buf][0];
#pragma unroll
        for (int k = 0; k < 8; k++) {
            const float* src = base + (size_t)(8 * k + rsub) * D_;
            __builtin_amdgcn_global_load_lds(
                (const __attribute__((address_space(1))) uint32_t*)src,
                (__attribute__((address_space(3))) uint32_t*)(dst + k * 256),
                16, 0, 0);
        }
    };

    // issue first chunk's loads, then fill W1 LDS (overlaps the load latency)
    stage(0, 0);
    {
        const f32x4* wsrc = (const f32x4*)W1;
        f32x4* wdst = (f32x4*)w1s;
#pragma unroll
        for (int q = 0; q < 20; q++) wdst[tid + 128 * q] = wsrc[tid + 128 * q];
    }
    __syncthreads();   // w1s visible (also drains vmcnt -> chunk 0 ready)

    // ---- dot phase: in-lane over wave's 512 d, 16 chunks of 32 d ----
    f32x2 acc2[5];
#pragma unroll
    for (int h = 0; h < 5; h++) acc2[h] = f32x2{0.f, 0.f};

#pragma unroll 1
    for (int c = 0; c < 16; c++) {
        if (c < 15) {
            stage((c + 1) & 1, c + 1);
            asm volatile("s_waitcnt vmcnt(8)" ::: "memory");   // chunk c's 8 done
        } else {
            asm volatile("s_waitcnt vmcnt(0)" ::: "memory");
        }
        __builtin_amdgcn_sched_barrier(0);

        const float* tb    = &stg[wave][c & 1][lane * 32];        // my t-row (128 B)
        const float* wbase = w1s + (size_t)(dof0 + c * 32) * U_;  // uniform -> broadcast
#pragma unroll
        for (int j = 0; j < 8; j++) {
            const f32x4 av = *(const f32x4*)(tb + ((j ^ (lane & 7)) << 2));
            const float* wd = wbase + j * 4 * U_;
            const float avv[4] = {av.x, av.y, av.z, av.w};
#pragma unroll
            for (int i = 0; i < 4; i++) {
                const f32x2 ax = f32x2{avv[i], avv[i]};
#pragma unroll
                for (int h = 0; h < 5; h++)
                    acc2[h] = pk_fma(ax, *(const f32x2*)(wd + i * U_ + 2 * h), acc2[h]);
            }
        }
    }

    // ---- combine partial dots across the 2 waves (pmat aliases dead stg) ----
    __syncthreads();   // all staging reads done before aliasing
#pragma unroll
    for (int h = 0; h < 5; h++)
        *(f32x2*)(&pmat[(wave * 64 + lane) * U_ + 2 * h]) = acc2[h];
    __syncthreads();

    // ---- e + exact softmax (wave 0 only; one DPP max+sum per block) ----
    if (wave == 0) {
        const float* cb = ws + WS_C + b * U_;   // uniform
        float e = b2[0];
#pragma unroll
        for (int u = 0; u < U_; u++) {
            float x = pmat[lane * U_ + u] + pmat[(64 + lane) * U_ + u] + cb[u];
            // tanh(x) = 1 - 2/(e^{2x}+1); exp2 saturates -> exact +-1 tails
            float ex = exp2f(x * 2.8853900817779268f);
            float th = 1.f - 2.f * __builtin_amdgcn_rcpf(ex + 1.f);
            e += th * W2[u];
        }
        e = fmaxf(e, 0.f);
        ws[WS_E + b * T_ + t0 + lane] = e;

        const float mb = wave_max_uniform(e);
        const float w  = exp2f((e - mb) * 1.4426950408889634f);
        const float Zb = wave_sum_uniform(w);
        wbuf[lane] = w;
        if (lane == 0) { ws[WS_PMZ + blk * 2] = mb; ws[WS_PMZ + blk * 2 + 1] = Zb; }
    }
    __syncthreads();

    // ---- weighted sum: thread owns 8 d's; tile re-read from L2/L3 ----
    f32x4 v0 = f32x4{0.f, 0.f, 0.f, 0.f};
    f32x4 v1 = f32x4{0.f, 0.f, 0.f, 0.f};
    const float* ap = a + arow0 + tid * 8;
#pragma unroll 8
    for (int t = 0; t < 64; t++) {
        const float wt = wbuf[t];   // uniform broadcast
        v0 += wt * *(const f32x4*)(ap + (size_t)t * D_);
        v1 += wt * *(const f32x4*)(ap + (size_t)t * D_ + 4);
    }
    ((f32x4*)(ws + WS_PV))[blk * 256 + tid * 2]     = v0;
    ((f32x4*)(ws + WS_PV))[blk * 256 + tid * 2 + 1] = v1;
}

// ---------------------------------------------------------------------------
// K2: final combine per batch (8 partials) -> context + scores
// ---------------------------------------------------------------------------
__global__ __launch_bounds__(256) void k2_final(const float* __restrict__ ws,
                                                float* __restrict__ out) {
    const int b = blockIdx.x;
    const int tid = threadIdx.x;

    float pm[8], pz[8];
    float mb = -1e30f;
#pragma unroll
    for (int p = 0; p < 8; p++) {
        pm[p] = ws[WS_PMZ + (b * 8 + p) * 2];
        pz[p] = ws[WS_PMZ + (b * 8 + p) * 2 + 1];
        mb = fmaxf(mb, pm[p]);
    }
    float f[8], Z = 0.f;
#pragma unroll
    for (int p = 0; p < 8; p++) { f[p] = __expf(pm[p] - mb); Z += f[p] * pz[p]; }
    const float rz = 1.f / Z;

    f32x4 o = f32x4{0.f, 0.f, 0.f, 0.f};
#pragma unroll
    for (int p = 0; p < 8; p++) {
        f32x4 t = ((const f32x4*)(ws + WS_PV))[(b * 8 + p) * 256 + tid];
        o += f[p] * t;
    }
    o *= rz;
    ((f32x4*)out)[b * 256 + tid] = o;

    for (int t = tid; t < T_; t += 256) {
        out[B_ * D_ + b * T_ + t] = __expf(ws[WS_E + b * T_ + t] - mb) * rz;
    }
}

// ---------------------------------------------------------------------------
extern "C" void kernel_launch(void* const* d_in, const int* in_sizes, int n_in,
                              void* d_out, int out_size, void* d_ws, size_t ws_size,
                              hipStream_t stream) {
    const float* a      = (const float*)d_in[0];
    const float* s_prev = (const float*)d_in[1];
    const float* W1     = (const float*)d_in[2];
    const float* b1     = (const float*)d_in[3];
    const float* W2     = (const float*)d_in[4];
    const float* b2     = (const float*)d_in[5];
    float* out = (float*)d_out;
    float* ws  = (float*)d_ws;

    k0_prep<<<dim3(B_), dim3(256), 0, stream>>>(s_prev, W1, b1, ws);
    k1_main<<<dim3(B_ * 8), dim3(128), 0, stream>>>(a, W1, W2, b2, ws);
    k2_final<<<dim3(B_), dim3(256), 0, stream>>>(ws, out);
}

// Round 6
// 217.092 us; speedup vs baseline: 1.6500x; 1.0183x over previous
//
#include <hip/hip_runtime.h>
#include <stdint.h>

// Problem constants
#define B_ 64
#define T_ 512
#define D_ 1024
#define S_ 1024
#define U_ 10

typedef float f32x2 __attribute__((ext_vector_type(2)));
typedef float f32x4 __attribute__((ext_vector_type(4)));

// workspace layout (in floats)
static constexpr int WS_PMZ = 0;        // [512][2]  per-block partial (m, Z)
static constexpr int WS_E   = 1024;     // [64][512] raw e values
static constexpr int WS_PV  = 33792;    // [512][1024] per-block partial weighted sums

// ---------------------------------------------------------------------------
// DPP wave64 sum -> uniform value.
// ---------------------------------------------------------------------------
template <int CTRL>
__device__ __forceinline__ float dpp_add(float x) {
    int yi = __builtin_amdgcn_update_dpp(0, __float_as_int(x), CTRL, 0xf, 0xf, true);
    return x + __int_as_float(yi);
}

__device__ __forceinline__ float wave_sum_uniform(float x) {
    x = dpp_add<0x111>(x);   // row_shr:1
    x = dpp_add<0x112>(x);   // row_shr:2
    x = dpp_add<0x114>(x);   // row_shr:4
    x = dpp_add<0x118>(x);   // row_shr:8
    x = dpp_add<0x142>(x);   // row_bcast15
    x = dpp_add<0x143>(x);   // row_bcast31 -> lane 63 = total
    return __int_as_float(__builtin_amdgcn_readlane(__float_as_int(x), 63));
}

__device__ __forceinline__ float uload(const float* p) {
    return __int_as_float(__builtin_amdgcn_readfirstlane(__float_as_int(*p)));
}
__device__ __forceinline__ float uniformf(float x) {
    return __int_as_float(__builtin_amdgcn_readfirstlane(__float_as_int(x)));
}

__device__ __forceinline__ f32x2 pk_fma(f32x2 a, f32x2 b, f32x2 c) {
#if __has_builtin(__builtin_elementwise_fma)
    return __builtin_elementwise_fma(a, b, c);
#else
    return a * b + c;
#endif
}

// ---------------------------------------------------------------------------
// K1: round-0 structure (512 blocks = 64 b x 8 chunks; 4 waves/block; wave
// owns 16 consecutive t; lane owns 16 d; w1p register-resident; online
// softmax in registers) + zero-VGPR LDS-ring staging for `a`:
//  - per-wave 4-slot ring stg[wave][slot][1024] filled by global_load_lds
//    (width 16, linear dest; lane*16B read pattern is conflict-free).
//  - counted s_waitcnt vmcnt(12): 3 t (~2700 cyc) always in flight, never
//    drained mid-loop -> HBM latency fully covered at 2 waves/SIMD.
// ---------------------------------------------------------------------------
__global__ __launch_bounds__(256, 2) void k1_main(const float* __restrict__ a,
                                                  const float* __restrict__ s_prev,
                                                  const float* __restrict__ W1,
                                                  const float* __restrict__ b1,
                                                  const float* __restrict__ W2,
                                                  const float* __restrict__ b2,
                                                  float* __restrict__ ws) {
    const int blk  = blockIdx.x;
    const int b    = blk >> 3;
    const int p    = blk & 7;
    const int tid  = threadIdx.x;
    const int wave = tid >> 6;
    const int lane = tid & 63;

    __shared__ __align__(16) float stg[4][4][1024];   // 64 KB staging ring
    __shared__ float mzs[4][2];

    // ---- Phase A: per-wave c[u] (issued BEFORE staging so its VMEM is older) ----
    float c[U_];
    {
        float cacc[U_];
#pragma unroll
        for (int u = 0; u < U_; u++) cacc[u] = 0.f;
#pragma unroll
        for (int r = 0; r < 4; r++) {
            const f32x4 s4 = *(const f32x4*)(s_prev + b * S_ + r * 256 + lane * 4);
            const float svv[4] = {s4.x, s4.y, s4.z, s4.w};
#pragma unroll
            for (int i = 0; i < 4; i++) {
                const int s = r * 256 + lane * 4 + i;
                const float* wp = W1 + (size_t)(D_ + s) * U_;
#pragma unroll
                for (int h = 0; h < 5; h++) {
                    f32x2 t2 = *(const f32x2*)(wp + 2 * h);
                    cacc[2 * h]     += svv[i] * t2.x;
                    cacc[2 * h + 1] += svv[i] * t2.y;
                }
            }
        }
#pragma unroll
        for (int u = 0; u < U_; u++)
            c[u] = uniformf(wave_sum_uniform(cacc[u]) + uload(b1 + u));
    }

    float w2v[U_];
#pragma unroll
    for (int u = 0; u < U_; u++) w2v[u] = uload(W2 + u);
    const float b2s = uload(b2);

    // ---- W1[:D] fragment, packed d-pairs (160 VGPRs) ----
    f32x2 w1p[4][2][U_];
#pragma unroll
    for (int k = 0; k < 4; k++) {
        const float* wp = W1 + (size_t)(k * 256 + lane * 4) * U_;
        float wbuf[40];
#pragma unroll
        for (int q = 0; q < 10; q++) {
            f32x4 t = *(const f32x4*)(wp + 4 * q);
            wbuf[4 * q + 0] = t.x; wbuf[4 * q + 1] = t.y;
            wbuf[4 * q + 2] = t.z; wbuf[4 * q + 3] = t.w;
        }
#pragma unroll
        for (int u = 0; u < U_; u++) {
            w1p[k][0][u] = f32x2{wbuf[u],      wbuf[10 + u]};
            w1p[k][1][u] = f32x2{wbuf[20 + u], wbuf[30 + u]};
        }
    }

    // ---- Phase B: online softmax over 16 t, LDS-ring staged ----
    f32x2 v2[4][2];
#pragma unroll
    for (int k = 0; k < 4; k++) { v2[k][0] = f32x2{0.f, 0.f}; v2[k][1] = f32x2{0.f, 0.f}; }
    float m = -1e30f, Z = 0.f;

    const int t0 = p * 64 + wave * 16;
    const size_t arow = (size_t)(b * T_ + t0) * D_;
    const float* asrc = a + arow + lane * 4;

    auto stage = [&](int tt) {
        const int slot = tt & 3;
        const float* src = asrc + (size_t)tt * D_;
#pragma unroll
        for (int k = 0; k < 4; k++) {
            __builtin_amdgcn_global_load_lds(
                (const __attribute__((address_space(1))) uint32_t*)(src + k * 256),
                (__attribute__((address_space(3))) uint32_t*)&stg[wave][slot][k * 256],
                16, 0, 0);
        }
    };

    auto body = [&](int tt) {
        const float* tb = &stg[wave][tt & 3][0];
        f32x4 av[4];
#pragma unroll
        for (int k = 0; k < 4; k++)
            av[k] = *(const f32x4*)(tb + k * 256 + lane * 4);

        f32x2 acc2[U_];
#pragma unroll
        for (int u = 0; u < U_; u++) acc2[u] = f32x2{0.f, 0.f};
#pragma unroll
        for (int k = 0; k < 4; k++) {
            const f32x2 alo = av[k].lo;
            const f32x2 ahi = av[k].hi;
#pragma unroll
            for (int u = 0; u < U_; u++) {
                acc2[u] = pk_fma(alo, w1p[k][0][u], acc2[u]);
                acc2[u] = pk_fma(ahi, w1p[k][1][u], acc2[u]);
            }
        }

        float tm[U_];
#pragma unroll
        for (int u = 0; u < U_; u++) {
            float s = wave_sum_uniform(acc2[u].x + acc2[u].y);
            float x = s + c[u];
            // tanh(x) = 1 - 2/(e^{2x}+1); exp2 saturates -> exact +-1 tails
            float ex = exp2f(x * 2.8853900817779268f);
            float th = 1.f - 2.f * __builtin_amdgcn_rcpf(ex + 1.f);
            tm[u] = th * w2v[u];
        }
        float e = ((tm[0] + tm[1]) + (tm[2] + tm[3])) +
                  ((tm[4] + tm[5]) + (tm[6] + tm[7])) +
                  ((tm[8] + tm[9]) + b2s);
        e = fmaxf(e, 0.f);
        if (lane == 0) ws[WS_E + b * T_ + t0 + tt] = e;

        if (e > m) {
            // new max: w = 1, rescale old state (rare, wave-uniform branch)
            float sc = exp2f((m - e) * 1.4426950408889634f);
            Z = Z * sc + 1.f;
            f32x2 scv = {sc, sc};
#pragma unroll
            for (int k = 0; k < 4; k++) {
                v2[k][0] = pk_fma(v2[k][0], scv, av[k].lo);
                v2[k][1] = pk_fma(v2[k][1], scv, av[k].hi);
            }
            m = e;
        } else {
            float w = exp2f((e - m) * 1.4426950408889634f);
            Z += w;
            f32x2 wv = {w, w};
#pragma unroll
            for (int k = 0; k < 4; k++) {
                v2[k][0] = pk_fma(wv, av[k].lo, v2[k][0]);
                v2[k][1] = pk_fma(wv, av[k].hi, v2[k][1]);
            }
        }
    };

    // prologue: 3 slots in flight before first use
    stage(0); stage(1); stage(2);

#pragma unroll 1
    for (int tt = 0; tt < 13; tt++) {
        stage(tt + 3);
        asm volatile("s_waitcnt vmcnt(12)" ::: "memory");   // slot tt ready
        __builtin_amdgcn_sched_barrier(0);
        body(tt);
    }
    asm volatile("s_waitcnt vmcnt(8)" ::: "memory");
    __builtin_amdgcn_sched_barrier(0);
    body(13);
    asm volatile("s_waitcnt vmcnt(4)" ::: "memory");
    __builtin_amdgcn_sched_barrier(0);
    body(14);
    asm volatile("s_waitcnt vmcnt(0)" ::: "memory");
    __builtin_amdgcn_sched_barrier(0);
    body(15);

    // ---- block combine across 4 waves (vs4 aliases the dead staging LDS) ----
    __syncthreads();   // all waves done reading their ring slots
    f32x4* vs4 = (f32x4*)&stg[0][0][0];   // [4][256] f32x4 = 16 KB
#pragma unroll
    for (int k = 0; k < 4; k++) {
        f32x4 o;
        o.lo = v2[k][0];
        o.hi = v2[k][1];
        vs4[wave * 256 + k * 64 + lane] = o;
    }
    if (lane == 0) { mzs[wave][0] = m; mzs[wave][1] = Z; }
    __syncthreads();

    float m0 = mzs[0][0], m1 = mzs[1][0], m2 = mzs[2][0], m3 = mzs[3][0];
    float mb = fmaxf(fmaxf(m0, m1), fmaxf(m2, m3));
    float f0 = __expf(m0 - mb), f1 = __expf(m1 - mb);
    float f2 = __expf(m2 - mb), f3 = __expf(m3 - mb);
    float Zb = f0 * mzs[0][1] + f1 * mzs[1][1] + f2 * mzs[2][1] + f3 * mzs[3][1];

    f32x4 t0v = vs4[0 * 256 + tid], t1v = vs4[1 * 256 + tid];
    f32x4 t2v = vs4[2 * 256 + tid], t3v = vs4[3 * 256 + tid];
    f32x4 o = f0 * t0v + f1 * t1v + f2 * t2v + f3 * t3v;
    ((f32x4*)(ws + WS_PV))[blk * 256 + tid] = o;
    if (tid == 0) { ws[WS_PMZ + blk * 2] = mb; ws[WS_PMZ + blk * 2 + 1] = Zb; }
}

// ---------------------------------------------------------------------------
// K2: final combine per batch (8 partials) -> context + scores
// ---------------------------------------------------------------------------
__global__ __launch_bounds__(256) void k2_final(const float* __restrict__ ws,
                                                float* __restrict__ out) {
    const int b = blockIdx.x;
    const int tid = threadIdx.x;

    float pm[8], pz[8];
    float mb = -1e30f;
#pragma unroll
    for (int p = 0; p < 8; p++) {
        pm[p] = ws[WS_PMZ + (b * 8 + p) * 2];
        pz[p] = ws[WS_PMZ + (b * 8 + p) * 2 + 1];
        mb = fmaxf(mb, pm[p]);
    }
    float f[8], Z = 0.f;
#pragma unroll
    for (int p = 0; p < 8; p++) { f[p] = __expf(pm[p] - mb); Z += f[p] * pz[p]; }
    const float rz = 1.f / Z;

    f32x4 o = f32x4{0.f, 0.f, 0.f, 0.f};
#pragma unroll
    for (int p = 0; p < 8; p++) {
        f32x4 t = ((const f32x4*)(ws + WS_PV))[(b * 8 + p) * 256 + tid];
        o += f[p] * t;
    }
    o *= rz;
    ((f32x4*)out)[b * 256 + tid] = o;

    for (int t = tid; t < T_; t += 256) {
        out[B_ * D_ + b * T_ + t] = __expf(ws[WS_E + b * T_ + t] - mb) * rz;
    }
}

// ---------------------------------------------------------------------------
extern "C" void kernel_launch(void* const* d_in, const int* in_sizes, int n_in,
                              void* d_out, int out_size, void* d_ws, size_t ws_size,
                              hipStream_t stream) {
    const float* a      = (const float*)d_in[0];
    const float* s_prev = (const float*)d_in[1];
    const float* W1     = (const float*)d_in[2];
    const float* b1     = (const float*)d_in[3];
    const float* W2     = (const float*)d_in[4];
    const float* b2     = (const float*)d_in[5];
    float* out = (float*)d_out;
    float* ws  = (float*)d_ws;

    k1_main<<<dim3(B_ * 8), dim3(256), 0, stream>>>(a, s_prev, W1, b1, W2, b2, ws);
    k2_final<<<dim3(B_), dim3(256), 0, stream>>>(ws, out);
}